// Round 16
// baseline (1550.564 us; speedup 1.0000x reference)
//
#include <hip/hip_runtime.h>

#define NN 1024
#define MM 1024
#define NB 16
#define BIGF 1.0e10f
#define TP 17                       // bwd tile pad
#define NW 8                        // fwd: waves per workgroup
#define OFS 5                       // fwd: interval offset between waves
#define CW 16                       // fwd: steps per interval
#define NA 68                       // fwd: active intervals per wave
#define NGI (OFS * (NW - 1) + NA)   // fwd: 103 global intervals

#define SQC 1.2011224087864498f    // sqrt(log2 e)
#define CLOG2E 1.4426950408889634f // log2 e
#define LN2F 0.6931471805599453f   // 1/log2 e

typedef float f32x4 __attribute__((ext_vector_type(4)));

#define EXP2F(x) __builtin_amdgcn_exp2f(x)
#define LOG2F(x) __builtin_amdgcn_logf(x)

// softmin3 in the log2-scaled domain (inputs/output are c*R values):
// r' = mn' - log2(1 + 2^(mn'-md') + 2^(mn'-mx'))   [always-one term elided]
__device__ __forceinline__ float softmin3s(float a, float b, float c) {
  const float mn = fminf(a, fminf(b, c));
  const float mx = fmaxf(a, fmaxf(b, c));
  const float md = __builtin_amdgcn_fmed3f(a, b, c);
  const float s = 1.0f + EXP2F(mn - md) + EXP2F(mn - mx);
  return mn - LOG2F(s);
}

// D[b,i,j] = (x[b,i] - y[j])^2 ; coalesced float4 writes
__global__ __launch_bounds__(256) void d_init_kernel(const float* __restrict__ x,
                                                     const float* __restrict__ y,
                                                     float* __restrict__ D) {
  size_t idx = ((size_t)blockIdx.x * blockDim.x + threadIdx.x) * 4;
  int j = (int)(idx & (MM - 1));
  size_t bi = idx >> 10;
  float xi = x[bi];
  const float4 yv = *reinterpret_cast<const float4*>(y + j);
  float t0 = xi - yv.x, t1 = xi - yv.y, t2 = xi - yv.z, t3 = xi - yv.w;
  float4 o;
  o.x = t0 * t0; o.y = t1 * t1; o.z = t2 * t2; o.w = t3 * t3;
  *reinterpret_cast<float4*>(D + idx) = o;
}

// R boundary: R[b,0,0]=0, R[b,0,j>=1]=BIG, R[b,i>=1,0]=BIG
__global__ __launch_bounds__(1024) void r_bound_kernel(float* __restrict__ R) {
  int b = blockIdx.x, t = threadIdx.x;
  float* Rb = R + (size_t)b * (NN + 1) * (MM + 1);
  Rb[t + 1] = BIGF;
  Rb[(size_t)(t + 1) * (MM + 1)] = BIGF;
  if (t == 0) Rb[0] = 0.0f;
}

// ---------------- forward (round-15, measured ~420us) -----------------------
__global__ __launch_bounds__(512) void sdtw_fwd(const float* __restrict__ x,
                                                const float* __restrict__ y,
                                                float* __restrict__ R,
                                                float* __restrict__ score) {
  __shared__ float tile[NW][2112];
  __shared__ float ringR[NW][128];
  const int b = blockIdx.x, t = threadIdx.x;
  const int w = t >> 6, l = t & 63;
  float* __restrict__ Rb = R + (size_t)b * (NN + 1) * (MM + 1);
  const int i1 = 128 * w + 2 * l + 1;
  const float x1 = x[b * NN + i1 - 1] * SQC;
  const float x2 = x[b * NN + i1] * SQC;
  float* tl = &tile[w][33 * l];
  const int wm1 = (w > 0) ? (w - 1) : 0;
  const bool L0 = (l == 0), W0 = (w == 0);
  const bool pub = (l == 63) && (w < NW - 1);
  float c1 = BIGF, c2 = BIGF, m1 = BIGF;
  float dgc = BIGF;  // carry: raw up-shuffle of previous step
  __syncthreads();
  for (int G = 0; G < NGI; ++G) {
    const int a = G - OFS * w;
    if (a >= 0 && a < NA) {
      const int s0 = a * CW;
      // hoisted inputs: y (global, L1-resident, pre-scaled) + boundary ring
      float yw[16], rgm[17];
#pragma unroll
      for (int p = 0; p < 16; ++p) {
        const int jy = s0 + p - l - 1;
        yw[p] = y[(jy >= 0 && jy < MM) ? jy : 0] * SQC;
      }
#pragma unroll
      for (int k = 0; k < 17; ++k) rgm[k] = ringR[wm1][(s0 + k - 1) & 127];
#pragma unroll
      for (int p = 0; p < CW; ++p) {
        const int j = s0 + p - l;
        const bool act = (j >= 1) && (j <= MM);
        const float up_raw = __shfl_up(m1, 1);  // R'(i1-1, j)
        float up = up_raw;
        float dg = dgc;                          // R'(i1-1, j-1) carry
        if (L0) {
          up = W0 ? BIGF : rgm[p + 1];
          dg = W0 ? ((j == 1) ? 0.0f : BIGF) : ((j == 1) ? BIGF : rgm[p]);
        }
        dgc = up_raw;
        const float yv = yw[p];
        float dv1 = x1 - yv; dv1 *= dv1;
        const float r1 = dv1 + softmin3s(dg, up, c1);
        float dv2 = x2 - yv; dv2 *= dv2;
        const float r2 = dv2 + softmin3s(c1, r1, c2);
        tl[p] = r1;
        tl[16 + p] = r2;
        if (pub && act) ringR[w][j & 127] = r2;
        m1 = act ? r2 : m1;
        c1 = act ? r1 : c1;
        c2 = act ? r2 : c2;
      }
      __builtin_amdgcn_wave_barrier();
      // cooperative coalesced store (unscale ×ln2 to true R)
#pragma unroll
      for (int g = 0; g < 32; ++g) {
        const int rr = 4 * g + (l >> 4);
        const int sl = l & 15;
        const int col = s0 + sl - (rr >> 1);
        const float v = tile[w][rr * 16 + (rr >> 1) + sl] * LN2F;
        if (col >= 1 && col <= MM)
          Rb[(size_t)(128 * w + 1 + rr) * (MM + 1) + col] = v;
      }
    }
    __syncthreads();
  }
  if (w == NW - 1 && l == 63) score[b] = m1 * LN2F;  // R[1024][1024]
}

// ---------------- backward (lockstep; shuffle exchange, min DS-pipe) --------
// Thread t owns row i=t+1. Neighbor (i+1) values come from __shfl_down of the
// rt-carries (lane l+1's post-step carry == old ebx/rbx value, same mask);
// wave-boundary rows (lane63 <- next wave's lane0) via 2x17 parity LDS slots.
// y hoisted per 16-diag block into registers from global (off the DS pipe).
// Full-width DS ops per step: tile read + tile write only.
__global__ __launch_bounds__(1024) void sdtw_bwd(const float* __restrict__ x,
                                                 const float* __restrict__ y,
                                                 const float* __restrict__ R,
                                                 float* __restrict__ E) {
  __shared__ float tile[NN][TP];
  __shared__ float bndE[2][17];
  __shared__ float bndR[2][17];
  const int b = blockIdx.x, t = threadIdx.x;
  const int i = t + 1;
  const int k = t >> 6, l = t & 63;
  const float* __restrict__ Rb = R + (size_t)b * (NN + 1) * (MM + 1);
  float* __restrict__ Eb = E + (size_t)b * (size_t)NN * MM;
  if (t < 34) { (&bndE[0][0])[t] = 0.0f; (&bndR[0][0])[t] = -BIGF; }
  const float xi = x[b * NN + t] * SQC;                              // X(i)
  const float xi1 = x[b * NN + ((t + 1 < NN) ? (t + 1) : t)] * SQC;  // X(i+1)
  const bool seedrow = (i == NN);
  const bool L63 = (l == 63), L0 = (l == 0);
  float rt_e = 0.0f, rt_r = -BIGF;    // own (i, j+1) @ d+1 carry
  float dgn_e = 0.0f, dgn_r = -BIGF;  // (i+1, j+1) @ d+2 carry
  // prologue: coop-load R tile for block K=128 (scale ×c)
#pragma unroll
  for (int pass = 0; pass < 4; ++pass) {
    const int row = (pass << 8) + (t >> 2);
    const int ir = row + 1;
    const int c4 = (t & 3) << 2;
    const int jb2 = (128 << 4) - ir + c4;
    if (jb2 >= 1 && jb2 + 3 <= MM) {
      const float4 v = *reinterpret_cast<const float4*>(Rb + (size_t)ir * (MM + 1) + jb2);
      tile[row][c4] = v.x * CLOG2E; tile[row][c4 + 1] = v.y * CLOG2E;
      tile[row][c4 + 2] = v.z * CLOG2E; tile[row][c4 + 3] = v.w * CLOG2E;
    } else {
#pragma unroll
      for (int c = 0; c < 4; ++c) {
        const int jc = jb2 + c;
        tile[row][c4 + c] = (jc >= 1 && jc <= MM)
                                ? Rb[(size_t)ir * (MM + 1) + jc] * CLOG2E
                                : -BIGF;
      }
    }
  }
  __syncthreads();

  for (int K = 128; K >= 0; --K) {
    const int d0 = K << 4;
    // y hoist: yw[u] = y'[d0 - i - 1 + u], u in [0,16] (global, L1)
    float yw[17];
#pragma unroll
    for (int u = 0; u < 17; ++u) {
      const int idx = d0 - i - 1 + u;
      yw[u] = (idx >= 0 && idx < MM) ? y[idx] * SQC : 0.0f;
    }
    float yj = yw[16];  // y'[j] at s=15
#pragma unroll
    for (int p = 0; p < 16; ++p) {
      const int s = 15 - p;  // descending d within block
      const int d = d0 + s;
      const int j = d - i;
      const bool act = (j >= 1) && (j <= MM);
      const int rp = (d + 1) & 1, wp = d & 1;
      float dn_e = __shfl_down(rt_e, 1);  // (i+1, j) @ d+1
      float dn_r = __shfl_down(rt_r, 1);
      if (L63) { dn_e = bndE[rp][k + 1]; dn_r = bndR[rp][k + 1]; }
      const float yjm1 = yw[s];
      const float rij = tile[t][s];
      float d1 = xi1 - yjm1; d1 *= d1;  // c*D(i+1, j)
      float d2 = xi - yj;    d2 *= d2;  // c*D(i,   j+1)
      float d3 = xi1 - yj;   d3 *= d3;  // c*D(i+1, j+1)
      float acc = dn_e * EXP2F(dn_r - rij - d1) + rt_e * EXP2F(rt_r - rij - d2) +
                  dgn_e * EXP2F(dgn_r - rij - d3);
      if (seedrow && j == MM) acc += 1.0f;
      tile[t][s] = act ? acc : 0.0f;  // in-place E
      rt_e = act ? acc : 0.0f;
      rt_r = act ? rij : -BIGF;
      dgn_e = dn_e; dgn_r = dn_r;
      if (L0 && k > 0) { bndE[wp][k] = rt_e; bndR[wp][k] = rt_r; }
      yj = yjm1;
      __syncthreads();
    }
    // coop: store E tile, then load R tile for block K-1 (scale ×c)
#pragma unroll
    for (int pass = 0; pass < 4; ++pass) {
      const int row = (pass << 8) + (t >> 2);
      const int ir = row + 1;
      const int c4 = (t & 3) << 2;
      const int jb2 = d0 - ir + c4;
      float fv[4];
#pragma unroll
      for (int c = 0; c < 4; ++c) fv[c] = tile[row][c4 + c];
      if (jb2 >= 1 && jb2 + 3 <= MM) {
        f32x4 v;
        v[0] = fv[0]; v[1] = fv[1]; v[2] = fv[2]; v[3] = fv[3];
        const float* pp = Eb + (size_t)row * MM + (jb2 - 1);
        asm volatile("global_store_dwordx4 %0, %1, off" ::"v"(pp), "v"(v) : "memory");
      } else if (jb2 + 3 >= 1 && jb2 <= MM) {
#pragma unroll
        for (int c = 0; c < 4; ++c) {
          const int jc = jb2 + c;
          if (jc >= 1 && jc <= MM) Eb[(size_t)row * MM + (jc - 1)] = fv[c];
        }
      }
      const int jn = jb2 - 16;  // next block window
      if (jn >= 1 && jn + 3 <= MM) {
        const float4 v = *reinterpret_cast<const float4*>(Rb + (size_t)ir * (MM + 1) + jn);
        tile[row][c4] = v.x * CLOG2E; tile[row][c4 + 1] = v.y * CLOG2E;
        tile[row][c4 + 2] = v.z * CLOG2E; tile[row][c4 + 3] = v.w * CLOG2E;
      } else {
#pragma unroll
        for (int c = 0; c < 4; ++c) {
          const int jc = jn + c;
          tile[row][c4 + c] = (jc >= 1 && jc <= MM)
                                  ? Rb[(size_t)ir * (MM + 1) + jc] * CLOG2E
                                  : -BIGF;
        }
      }
    }
    __syncthreads();
  }
}

extern "C" void kernel_launch(void* const* d_in, const int* in_sizes, int n_in,
                              void* d_out, int out_size, void* d_ws, size_t ws_size,
                              hipStream_t stream) {
  const float* x = (const float*)d_in[0];  // [16, 1024]
  const float* y = (const float*)d_in[1];  // [1024]
  float* out = (float*)d_out;
  float* score = out;                               // [16]
  float* D = out + NB;                              // [16,1024,1024]
  float* R = D + (size_t)NB * NN * MM;              // [16,1025,1025]
  float* E = R + (size_t)NB * (NN + 1) * (MM + 1);  // [16,1024,1024]

  hipLaunchKernelGGL(d_init_kernel, dim3((NB * NN * MM) / (256 * 4)), dim3(256), 0, stream,
                     x, y, D);
  hipLaunchKernelGGL(r_bound_kernel, dim3(NB), dim3(1024), 0, stream, R);
  hipLaunchKernelGGL(sdtw_fwd, dim3(NB), dim3(512), 0, stream, x, y, R, score);
  hipLaunchKernelGGL(sdtw_bwd, dim3(NB), dim3(1024), 0, stream, x, y, R, E);
}

// Round 17
// 1181.678 us; speedup vs baseline: 1.3122x; 1.3122x over previous
//
#include <hip/hip_runtime.h>

#define NN 1024
#define MM 1024
#define NB 16
#define BIGF 1.0e10f
#define TP 17                       // bwd tile pad
#define NW 8                        // fwd: waves per workgroup
#define OFS 5                       // fwd: interval offset between waves
#define CW 16                       // fwd: steps per interval
#define NA 68                       // fwd: active intervals per wave
#define NGI (OFS * (NW - 1) + NA)   // fwd: 103 global intervals

#define SQC 1.2011224087864498f    // sqrt(log2 e)
#define CLOG2E 1.4426950408889634f // log2 e
#define LN2F 0.6931471805599453f   // 1/log2 e

typedef float f32x4 __attribute__((ext_vector_type(4)));

#define EXP2F(x) __builtin_amdgcn_exp2f(x)
#define LOG2F(x) __builtin_amdgcn_logf(x)

// softmin3 in the log2-scaled domain (inputs/output are c*R values):
// r' = mn' - log2(1 + 2^(mn'-md') + 2^(mn'-mx'))   [always-one term elided]
__device__ __forceinline__ float softmin3s(float a, float b, float c) {
  const float mn = fminf(a, fminf(b, c));
  const float mx = fmaxf(a, fmaxf(b, c));
  const float md = __builtin_amdgcn_fmed3f(a, b, c);
  const float s = 1.0f + EXP2F(mn - md) + EXP2F(mn - mx);
  return mn - LOG2F(s);
}

// D[b,i,j] = (x[b,i] - y[j])^2 ; coalesced float4 writes
__global__ __launch_bounds__(256) void d_init_kernel(const float* __restrict__ x,
                                                     const float* __restrict__ y,
                                                     float* __restrict__ D) {
  size_t idx = ((size_t)blockIdx.x * blockDim.x + threadIdx.x) * 4;
  int j = (int)(idx & (MM - 1));
  size_t bi = idx >> 10;
  float xi = x[bi];
  const float4 yv = *reinterpret_cast<const float4*>(y + j);
  float t0 = xi - yv.x, t1 = xi - yv.y, t2 = xi - yv.z, t3 = xi - yv.w;
  float4 o;
  o.x = t0 * t0; o.y = t1 * t1; o.z = t2 * t2; o.w = t3 * t3;
  *reinterpret_cast<float4*>(D + idx) = o;
}

// R boundary: R[b,0,0]=0, R[b,0,j>=1]=BIG, R[b,i>=1,0]=BIG
__global__ __launch_bounds__(1024) void r_bound_kernel(float* __restrict__ R) {
  int b = blockIdx.x, t = threadIdx.x;
  float* Rb = R + (size_t)b * (NN + 1) * (MM + 1);
  Rb[t + 1] = BIGF;
  Rb[(size_t)(t + 1) * (MM + 1)] = BIGF;
  if (t == 0) Rb[0] = 0.0f;
}

// ---------------- forward (round-15 + vectorized coop store) ----------------
__global__ __launch_bounds__(512) void sdtw_fwd(const float* __restrict__ x,
                                                const float* __restrict__ y,
                                                float* __restrict__ R,
                                                float* __restrict__ score) {
  __shared__ float tile[NW][2112];
  __shared__ float ringR[NW][128];
  const int b = blockIdx.x, t = threadIdx.x;
  const int w = t >> 6, l = t & 63;
  float* __restrict__ Rb = R + (size_t)b * (NN + 1) * (MM + 1);
  const int i1 = 128 * w + 2 * l + 1;
  const float x1 = x[b * NN + i1 - 1] * SQC;
  const float x2 = x[b * NN + i1] * SQC;
  float* tl = &tile[w][33 * l];
  const int wm1 = (w > 0) ? (w - 1) : 0;
  const bool L0 = (l == 0), W0 = (w == 0);
  const bool pub = (l == 63) && (w < NW - 1);
  float c1 = BIGF, c2 = BIGF, m1 = BIGF;
  float dgc = BIGF;  // carry: raw up-shuffle of previous step
  __syncthreads();
  for (int G = 0; G < NGI; ++G) {
    const int a = G - OFS * w;
    if (a >= 0 && a < NA) {
      const int s0 = a * CW;
      // hoisted inputs: y (global, L1-resident, pre-scaled) + boundary ring
      float yw[16], rgm[17];
#pragma unroll
      for (int p = 0; p < 16; ++p) {
        const int jy = s0 + p - l - 1;
        yw[p] = y[(jy >= 0 && jy < MM) ? jy : 0] * SQC;
      }
#pragma unroll
      for (int k = 0; k < 17; ++k) rgm[k] = ringR[wm1][(s0 + k - 1) & 127];
#pragma unroll
      for (int p = 0; p < CW; ++p) {
        const int j = s0 + p - l;
        const bool act = (j >= 1) && (j <= MM);
        const float up_raw = __shfl_up(m1, 1);  // R'(i1-1, j)
        float up = up_raw;
        float dg = dgc;                          // R'(i1-1, j-1) carry
        if (L0) {
          up = W0 ? BIGF : rgm[p + 1];
          dg = W0 ? ((j == 1) ? 0.0f : BIGF) : ((j == 1) ? BIGF : rgm[p]);
        }
        dgc = up_raw;
        const float yv = yw[p];
        float dv1 = x1 - yv; dv1 *= dv1;
        const float r1 = dv1 + softmin3s(dg, up, c1);
        float dv2 = x2 - yv; dv2 *= dv2;
        const float r2 = dv2 + softmin3s(c1, r1, c2);
        tl[p] = r1;
        tl[16 + p] = r2;
        if (pub && act) ringR[w][j & 127] = r2;
        m1 = act ? r2 : m1;
        c1 = act ? r1 : c1;
        c2 = act ? r2 : c2;
      }
      __builtin_amdgcn_wave_barrier();
      // cooperative coalesced store (unscale ×ln2), 4 cols/lane dwordx4:
      // lane handles row rr=16g+(l>>2), cols c4..c4+3 (c4=(l&3)*4).
#pragma unroll
      for (int g = 0; g < 8; ++g) {
        const int rr = 16 * g + (l >> 2);
        const int c4 = (l & 3) << 2;
        const int col0 = s0 + c4 - (rr >> 1);
        const int base = rr * 16 + (rr >> 1) + c4;
        const size_t goff = (size_t)(128 * w + 1 + rr) * (MM + 1);
        if (col0 >= 1 && col0 + 3 <= MM) {
          f32x4 v;
          v[0] = tile[w][base] * LN2F;
          v[1] = tile[w][base + 1] * LN2F;
          v[2] = tile[w][base + 2] * LN2F;
          v[3] = tile[w][base + 3] * LN2F;
          const float* pp = Rb + goff + col0;
          asm volatile("global_store_dwordx4 %0, %1, off" ::"v"(pp), "v"(v)
                       : "memory");
        } else if (col0 + 3 >= 1 && col0 <= MM) {
#pragma unroll
          for (int c = 0; c < 4; ++c) {
            const int jc = col0 + c;
            if (jc >= 1 && jc <= MM) Rb[goff + jc] = tile[w][base + c] * LN2F;
          }
        }
      }
    }
    __syncthreads();
  }
  if (w == NW - 1 && l == 63) score[b] = m1 * LN2F;  // R[1024][1024]
}

// ---------------- backward (round-15 verbatim, measured 836us) --------------
__global__ __launch_bounds__(1024) void sdtw_bwd(const float* __restrict__ x,
                                                 const float* __restrict__ y,
                                                 const float* __restrict__ R,
                                                 float* __restrict__ E) {
  __shared__ float ypad[3088];  // ypad[k] = y[k-1025]*sqrt(c), zeros outside
  __shared__ float rbx[4][NN + 2];
  __shared__ float ebx[4][NN + 2];
  __shared__ float tile[NN][TP];
  const int b = blockIdx.x, t = threadIdx.x;
  const int i = t + 1;
  const float* __restrict__ Rb = R + (size_t)b * (NN + 1) * (MM + 1);
  float* __restrict__ Eb = E + (size_t)b * (size_t)NN * MM;
  for (int k = t; k < 3088; k += 1024)
    ypad[k] = (k >= 1025 && k < 1025 + MM) ? y[k - 1025] * SQC : 0.0f;
#pragma unroll
  for (int q = 0; q < 4; ++q) { rbx[q][i] = -BIGF; ebx[q][i] = 0.0f; }
  if (t == NN - 1) {
#pragma unroll
    for (int q = 0; q < 4; ++q) { rbx[q][NN + 1] = -BIGF; ebx[q][NN + 1] = 0.0f; }
  }
  const float xi = x[b * NN + t] * SQC;                              // X(i)
  const float xi1 = x[b * NN + ((t + 1 < NN) ? (t + 1) : t)] * SQC;  // X(i+1)
  const bool seedrow = (i == NN);
  float rt_e = 0.0f, rt_r = -BIGF;    // (i, j+1) carries
  float dgn_e = 0.0f, dgn_r = -BIGF;  // (i+1, j+1) carries
  // prologue: coop-load R tile for block K=128 (scale ×c)
#pragma unroll
  for (int pass = 0; pass < 4; ++pass) {
    const int row = (pass << 8) + (t >> 2);
    const int ir = row + 1;
    const int c4 = (t & 3) << 2;
    const int jb2 = (128 << 4) - ir + c4;
    if (jb2 >= 1 && jb2 + 3 <= MM) {
      const float4 v = *reinterpret_cast<const float4*>(Rb + (size_t)ir * (MM + 1) + jb2);
      tile[row][c4] = v.x * CLOG2E; tile[row][c4 + 1] = v.y * CLOG2E;
      tile[row][c4 + 2] = v.z * CLOG2E; tile[row][c4 + 3] = v.w * CLOG2E;
    } else {
#pragma unroll
      for (int c = 0; c < 4; ++c) {
        const int jc = jb2 + c;
        tile[row][c4 + c] = (jc >= 1 && jc <= MM)
                                ? Rb[(size_t)ir * (MM + 1) + jc] * CLOG2E
                                : -BIGF;
      }
    }
  }
  __syncthreads();
  float yj = ypad[3088 - i];  // y'[j] seed at d=2063 (j = 2063 - i)

  for (int K = 128; K >= 0; --K) {
    const int d0 = K << 4;
#pragma unroll
    for (int p = 0; p < 16; ++p) {
      const int s = 15 - p;  // descending d within block
      const int d = d0 + s;
      const int j = d - i;
      const bool act = (j >= 1) && (j <= MM);
      const float dn_r = rbx[(s + 1) & 3][i + 1];  // (i+1, j) at diag d+1
      const float dn_e = ebx[(s + 1) & 3][i + 1];
      const float yjm1 = ypad[j + 1024];           // y'[j-1], pad-zero outside
      const float rij = tile[t][s];
      float d1 = xi1 - yjm1; d1 *= d1;  // c*D(i+1, j)
      float d2 = xi - yj;    d2 *= d2;  // c*D(i,   j+1)
      float d3 = xi1 - yj;   d3 *= d3;  // c*D(i+1, j+1)
      const float a1 = dn_r - rij - d1;
      const float a2 = rt_r - rij - d2;
      const float a3 = dgn_r - rij - d3;
      float acc = dn_e * EXP2F(a1) + rt_e * EXP2F(a2) + dgn_e * EXP2F(a3);
      if (seedrow && j == MM) acc += 1.0f;
      rbx[s & 3][i] = act ? rij : -BIGF;
      ebx[s & 3][i] = act ? acc : 0.0f;
      tile[t][s] = act ? acc : 0.0f;  // in-place E
      rt_e = act ? acc : 0.0f;
      rt_r = act ? rij : -BIGF;
      dgn_e = dn_e; dgn_r = dn_r;
      yj = yjm1;
      __syncthreads();
    }
    // coop: store E tile, then load R tile for block K-1 (scale ×c)
#pragma unroll
    for (int pass = 0; pass < 4; ++pass) {
      const int row = (pass << 8) + (t >> 2);
      const int ir = row + 1;
      const int c4 = (t & 3) << 2;
      const int jb2 = d0 - ir + c4;
      float fv[4];
#pragma unroll
      for (int c = 0; c < 4; ++c) fv[c] = tile[row][c4 + c];
      if (jb2 >= 1 && jb2 + 3 <= MM) {
        f32x4 v;
        v[0] = fv[0]; v[1] = fv[1]; v[2] = fv[2]; v[3] = fv[3];
        const float* pp = Eb + (size_t)row * MM + (jb2 - 1);
        asm volatile("global_store_dwordx4 %0, %1, off" ::"v"(pp), "v"(v) : "memory");
      } else if (jb2 + 3 >= 1 && jb2 <= MM) {
#pragma unroll
        for (int c = 0; c < 4; ++c) {
          const int jc = jb2 + c;
          if (jc >= 1 && jc <= MM) Eb[(size_t)row * MM + (jc - 1)] = fv[c];
        }
      }
      const int jn = jb2 - 16;  // next block window
      if (jn >= 1 && jn + 3 <= MM) {
        const float4 v = *reinterpret_cast<const float4*>(Rb + (size_t)ir * (MM + 1) + jn);
        tile[row][c4] = v.x * CLOG2E; tile[row][c4 + 1] = v.y * CLOG2E;
        tile[row][c4 + 2] = v.z * CLOG2E; tile[row][c4 + 3] = v.w * CLOG2E;
      } else {
#pragma unroll
        for (int c = 0; c < 4; ++c) {
          const int jc = jn + c;
          tile[row][c4 + c] = (jc >= 1 && jc <= MM)
                                  ? Rb[(size_t)ir * (MM + 1) + jc] * CLOG2E
                                  : -BIGF;
        }
      }
    }
    __syncthreads();
  }
}

extern "C" void kernel_launch(void* const* d_in, const int* in_sizes, int n_in,
                              void* d_out, int out_size, void* d_ws, size_t ws_size,
                              hipStream_t stream) {
  const float* x = (const float*)d_in[0];  // [16, 1024]
  const float* y = (const float*)d_in[1];  // [1024]
  float* out = (float*)d_out;
  float* score = out;                               // [16]
  float* D = out + NB;                              // [16,1024,1024]
  float* R = D + (size_t)NB * NN * MM;              // [16,1025,1025]
  float* E = R + (size_t)NB * (NN + 1) * (MM + 1);  // [16,1024,1024]

  hipLaunchKernelGGL(d_init_kernel, dim3((NB * NN * MM) / (256 * 4)), dim3(256), 0, stream,
                     x, y, D);
  hipLaunchKernelGGL(r_bound_kernel, dim3(NB), dim3(1024), 0, stream, R);
  hipLaunchKernelGGL(sdtw_fwd, dim3(NB), dim3(512), 0, stream, x, y, R, score);
  hipLaunchKernelGGL(sdtw_bwd, dim3(NB), dim3(1024), 0, stream, x, y, R, E);
}